// Round 11
// baseline (474.971 us; speedup 1.0000x reference)
//
#include <hip/hip_runtime.h>

// ConceptEmbedding: out = 0.1*e_free + 0.9*centroid[argmin d2]
// e_free = (seq @ emb) / rowsum(seq);  seq [8192 x 8192] f32, emb [8192 x 256] f32
// Strategy: split-precision bf16 MFMA (hi/lo, 3 passes) ~= f32 accuracy.
//   K0: pack emb (32x32x16 frag order) and cent-0.5 (16x16 order); f64 cnorm.
//   K1: BM=128 x BN=256, BK=64, split-K=8 (512 WGs, 2 blocks/CU), 8 waves.
//       Wave tile = 1 m-tile x 4 n-tiles (32x128) via 32x32x16 MFMA:
//       per K16/CU: LDS ~576 cyc << MFMA 1536 cyc (2.7x headroom; R7 was 1:1,
//       R10's 2m2n fix spilled at 64acc+64arch). Registers: acc 64 AGPR +
//       B single-set 32 + areg 8 + frags 8 + addr ~12 = ~126 <= 128 cap.
//       A f32->bf16 hi/lo staged via VALU to LDS (R5 zero-conflict swizzle),
//       B frags direct-from-global (L2-resident), one barrier per K64 step.
//   K2: reduce 8 partials -> e_free; mean-shifted MFMA vs centroids; f64 argmin; blend.

typedef unsigned short u16;
typedef unsigned int   u32;
using bf16x8 = __attribute__((ext_vector_type(8))) short;
using f32x4  = __attribute__((ext_vector_type(4))) float;
using f32x16 = __attribute__((ext_vector_type(16))) float;

#define MFMA_B16(A,B,C) __builtin_amdgcn_mfma_f32_16x16x32_bf16((A),(B),(C),0,0,0)
#define MFMA32(A,B,C)   __builtin_amdgcn_mfma_f32_32x32x16_bf16((A),(B),(C),0,0,0)

#define NSPLIT 8

static __device__ __forceinline__ u16 f2bf(float f){
  u32 u = __builtin_bit_cast(u32, f);
  u += 0x7FFFu + ((u >> 16) & 1u);   // RNE
  return (u16)(u >> 16);
}
static __device__ __forceinline__ u16 f2bf_fast(float f){
  u32 u = __builtin_bit_cast(u32, f);
  return (u16)((u + 0x8000u) >> 16); // round-nearest ties-away, branchless
}
static __device__ __forceinline__ float bf2f(u16 h){
  u32 u = ((u32)h) << 16;
  return __builtin_bit_cast(float, u);
}
static __device__ __forceinline__ void split2(float va, float vb, u32& hw, u32& lw){
  u16 ha = f2bf(va), hb = f2bf(vb);
  hw = (u32)ha | ((u32)hb << 16);
  lw = (u32)f2bf(va - bf2f(ha)) | ((u32)f2bf(vb - bf2f(hb)) << 16);
}
static __device__ __forceinline__ void split2f(float va, float vb, u32& hw, u32& lw){
  u16 ha = f2bf_fast(va), hb = f2bf_fast(vb);
  hw = (u32)ha | ((u32)hb << 16);
  lw = (u32)f2bf_fast(va - bf2f(ha)) | ((u32)f2bf_fast(vb - bf2f(hb)) << 16);
}

// ---------------- ws layout (bytes) ----------------
#define SZ_PART    ((size_t)NSPLIT*8192UL*256UL*4UL)   // 67,108,864  f32 partials [8][8192][256]
#define OFF_CNT    (SZ_PART)
#define SZ_CNT     ((size_t)NSPLIT*8192UL*4UL)
#define OFF_BHI    (OFF_CNT + SZ_CNT)
#define SZ_BHI     (8192UL*256UL*2UL)                  // 4 MB
#define OFF_BLO    (OFF_BHI + SZ_BHI)
#define OFF_CTHI   (OFF_BLO + SZ_BHI)
#define SZ_CT      (512UL*256UL*2UL)                   // 256 KB
#define OFF_CTLO   (OFF_CTHI + SZ_CT)
#define OFF_CNORM  (OFF_CTLO + SZ_CT)                  // 512 doubles

// ---------------- K0: pack B (32x32 order) / CT (16x16 order), cnorm ----------------
__global__ __launch_bounds__(256) void ce_prep(
    const float* __restrict__ emb, const float* __restrict__ cent,
    u16* __restrict__ Bhi, u16* __restrict__ Blo,
    u16* __restrict__ CThi, u16* __restrict__ CTlo,
    double* __restrict__ cnormd)
{
  const int b = blockIdx.x, t = threadIdx.x;
  const int l = t & 63;
  if (b < 1024) {
    // emb frag for 32x32x16: (nt 0..7, ksg 0..511): elem j = emb[ksg*16 + (l>>5)*8 + j][nt*32 + (l&31)]
    const int g  = b * 4 + (t >> 6);
    const int nt = g >> 9, ksg = g & 511;
    const int col = nt*32 + (l & 31);
    const int k0  = ksg*16 + (l >> 5)*8;
    u32 hw[4], lw[4];
    #pragma unroll
    for (int p = 0; p < 4; ++p) {
      float va = emb[(size_t)(k0 + 2*p    )*256 + col];
      float vb = emb[(size_t)(k0 + 2*p + 1)*256 + col];
      split2(va, vb, hw[p], lw[p]);
    }
    const size_t fi = ((size_t)nt*512 + ksg)*64 + l;
    *(uint4*)(Bhi + fi*8) = make_uint4(hw[0],hw[1],hw[2],hw[3]);
    *(uint4*)(Blo + fi*8) = make_uint4(lw[0],lw[1],lw[2],lw[3]);
  } else if (b < 1088) {               // cent^T frags (16x16 order; nt 0..31, ksg 0..7), shifted by -0.5
    const int lr = l & 15, lk = l >> 4;
    const int g  = (b - 1024) * 4 + (t >> 6);
    const int nt = g >> 3, ksg = g & 7;
    u32 hw[4], lw[4];
    #pragma unroll
    for (int p = 0; p < 4; ++p) {
      float va = cent[(size_t)(nt*16 + lr)*256 + ksg*32 + lk*8 + 2*p    ] - 0.5f;
      float vb = cent[(size_t)(nt*16 + lr)*256 + ksg*32 + lk*8 + 2*p + 1] - 0.5f;
      split2(va, vb, hw[p], lw[p]);
    }
    const size_t fi = ((size_t)nt*8 + ksg)*64 + l;
    *(uint4*)(CThi + fi*8) = make_uint4(hw[0],hw[1],hw[2],hw[3]);
    *(uint4*)(CTlo + fi*8) = make_uint4(lw[0],lw[1],lw[2],lw[3]);
  } else {                             // cnorm: |cent_k - 0.5|^2 in f64
    const int row = (b - 1088)*8 + (t >> 5);
    const int h = t & 31;
    double s = 0.0;
    #pragma unroll
    for (int j = 0; j < 8; ++j) {
      float x = cent[(size_t)row*256 + h*8 + j] - 0.5f;
      s += (double)x * (double)x;
    }
    #pragma unroll
    for (int off = 16; off > 0; off >>= 1) s += __shfl_xor(s, off);
    if (h == 0) cnormd[row] = s;
  }
}

// ---------------- K1: main split-bf16 GEMM (32x32x16), 512 WGs x 512 thr ----------------
// blk: mt = blk>>3 (row tile of 128), ks = blk&7 (K-eighth of 1024); BK=64, 16 steps
__global__ __launch_bounds__(512, 4) void ce_gemm(
    const float* __restrict__ seq,
    const u16* __restrict__ Bhi, const u16* __restrict__ Blo,
    float* __restrict__ part, float* __restrict__ cntpart)
{
  __shared__ char Ah[2][128*128];     // [buf][row*128B], 8 slots x 16B, swizzled; 32 KB
  __shared__ char Al[2][128*128];     // 32 KB; total 64 KB -> 2 blocks/CU

  const int t   = threadIdx.x;
  const int blk = blockIdx.x;
  const int mt  = blk >> 3;
  const int ks  = blk & 7;
  const size_t rowBase = (size_t)mt * 128;
  const int ar  = t >> 2;             // staging row 0..127
  const int ac  = t & 3;              // 16-float k-chunk within 64-col step
  const float* aptr = seq + (rowBase + ar) * 8192 + (size_t)ks * 1024 + ac * 16;

  const int w = t >> 6, l = t & 63;
  const int wm = w & 3, nh = w >> 2;  // wave: m-tile wm (32 rows), n-half nh (4 n-tiles)
  const int lrow = l & 31, lhi = l >> 5;

  f32x16 acc0, acc1, acc2, acc3;      // 4 n-tiles
  #pragma unroll
  for (int i = 0; i < 16; ++i) { acc0[i]=0.f; acc1[i]=0.f; acc2[i]=0.f; acc3[i]=0.f; }

  float csum = 0.f;
  float4 ar0, ar1;                    // 8-float staging buffer (one half)

  // B byte-offsets (u32) for the 4 n-tiles at current K16 index; +1024B per K16
  const char* bhp = (const char*)Bhi;
  const char* blp = (const char*)Blo;
  u32 boff0, boff1, boff2, boff3;
  {
    const u32 kb0 = (u32)ks * 64;
    boff0 = (((u32)(nh*4 + 0)*512 + kb0)*64 + (u32)l) * 16;
    boff1 = (((u32)(nh*4 + 1)*512 + kb0)*64 + (u32)l) * 16;
    boff2 = (((u32)(nh*4 + 2)*512 + kb0)*64 + (u32)l) * 16;
    boff3 = (((u32)(nh*4 + 3)*512 + kb0)*64 + (u32)l) * 16;
  }
  bf16x8 bh0, bh1, bh2, bh3, bl0, bl1, bl2, bl3;

  auto loadB = [&](void) {
    bh0 = *(const bf16x8*)(bhp + boff0);  bl0 = *(const bf16x8*)(blp + boff0);
    bh1 = *(const bf16x8*)(bhp + boff1);  bl1 = *(const bf16x8*)(blp + boff1);
    bh2 = *(const bf16x8*)(bhp + boff2);  bl2 = *(const bf16x8*)(blp + boff2);
    bh3 = *(const bf16x8*)(bhp + boff3);  bl3 = *(const bf16x8*)(blp + boff3);
    boff0 += 1024; boff1 += 1024; boff2 += 1024; boff3 += 1024;
  };
  // stage one 8-float half (h = 0/1) of this thread's 16-float chunk into buf
  auto stage_half = [&](int buf, int h) {
    float v[8] = {ar0.x, ar0.y, ar0.z, ar0.w, ar1.x, ar1.y, ar1.z, ar1.w};
    #pragma unroll
    for (int i = 0; i < 8; ++i) csum += v[i];
    u32 hw[4], lw[4];
    #pragma unroll
    for (int p = 0; p < 4; ++p) split2f(v[2*p], v[2*p+1], hw[p], lw[p]);
    const int slot = ac*2 + h;                       // 0..7
    const int off  = ar*128 + ((slot ^ (ar & 7)) << 4);
    *(uint4*)(Ah[buf] + off) = make_uint4(hw[0],hw[1],hw[2],hw[3]);
    *(uint4*)(Al[buf] + off) = make_uint4(lw[0],lw[1],lw[2],lw[3]);
  };
  auto loadA_half = [&](int h) {
    ar0 = *(const float4*)(aptr + h*8);
    ar1 = *(const float4*)(aptr + h*8 + 4);
  };
  // one K16 substep: 2 LDS reads (hi/lo) + 12 MFMA
  auto cluster = [&](int buf, int ksub) {
    const int row  = wm*32 + lrow;
    const int slot = ksub*2 + lhi;
    const int off  = row*128 + ((slot ^ (row & 7)) << 4);
    bf16x8 ah = *(const bf16x8*)(Ah[buf] + off);
    bf16x8 al = *(const bf16x8*)(Al[buf] + off);
    __builtin_amdgcn_s_setprio(1);
    acc0 = MFMA32(ah, bh0, acc0);
    acc1 = MFMA32(ah, bh1, acc1);
    acc2 = MFMA32(ah, bh2, acc2);
    acc3 = MFMA32(ah, bh3, acc3);
    acc0 = MFMA32(al, bh0, acc0);
    acc1 = MFMA32(al, bh1, acc1);
    acc2 = MFMA32(al, bh2, acc2);
    acc3 = MFMA32(al, bh3, acc3);
    acc0 = MFMA32(ah, bl0, acc0);
    acc1 = MFMA32(ah, bl1, acc1);
    acc2 = MFMA32(ah, bl2, acc2);
    acc3 = MFMA32(ah, bl3, acc3);
    __builtin_amdgcn_s_setprio(0);
  };

  // prologue: stage step 0 into buf0; advance aptr to step 1
  loadA_half(0);  stage_half(0, 0);
  loadA_half(1);  stage_half(0, 1);
  aptr += 64;
  __syncthreads();

  for (int step = 0; step < 16; ++step) {
    const int cur = step & 1;
    const bool more = (step < 15);

    loadB();                              // B for ksub0
    if (more) loadA_half(0);              // A half0 of next tile (global)
    cluster(cur, 0);

    loadB();                              // B for ksub1
    if (more) { stage_half(cur^1, 0); loadA_half(1); }
    cluster(cur, 1);

    loadB();                              // B for ksub2
    if (more) stage_half(cur^1, 1);
    cluster(cur, 2);

    loadB();                              // B for ksub3
    cluster(cur, 3);

    if (more) aptr += 64;
    __syncthreads();
  }

  // count partials: 4 lanes (same ar) shuffle-reduce, lane (t&3)==0 writes
  {
    float c = csum;
    c += __shfl_xor(c, 1);
    c += __shfl_xor(c, 2);
    if ((t & 3) == 0) cntpart[(size_t)ks*8192 + rowBase + ar] = c;
  }
  // partial e_free store (32x32 C/D: col = l&31, row = (reg&3) + 8*(reg>>2) + 4*(l>>5))
  float* pbase = part + ((size_t)ks*8192 + rowBase)*256;
  const int colBase = nh*128 + lrow;
  const int rowW = wm*32;
  #pragma unroll
  for (int reg = 0; reg < 16; ++reg) {
    const int rsub = (reg & 3) + 8*(reg >> 2) + 4*lhi;
    float* prow = pbase + (size_t)(rowW + rsub)*256 + colBase;
    prow[0]  = acc0[reg];
    prow[32] = acc1[reg];
    prow[64] = acc2[reg];
    prow[96] = acc3[reg];
  }
}

// ---------------- K2: reduce + centroid argmin + blend, 256 WGs x 256 thr ----------------
__global__ __launch_bounds__(256) void ce_cent(
    const float* __restrict__ part, const float* __restrict__ cntpart,
    const u16* __restrict__ CThi, const u16* __restrict__ CTlo,
    const double* __restrict__ cnormd, const float* __restrict__ cent,
    float* __restrict__ out)
{
  __shared__ float eL[32][256];       // e_free rows (f32)
  __shared__ char Eh[32*512];         // shifted e hi bf16, swizzled [row][256]
  __shared__ char El[32*512];
  __shared__ float GL[32][512];       // (e-.5)·(c-.5)^T
  __shared__ float cntL[32];
  __shared__ float enred[32][8];
  __shared__ float enL[32];

  const int t = threadIdx.x;
  const size_t rb = (size_t)blockIdx.x * 32;
  const int r  = t >> 3;
  const int c0 = (t & 7) * 32;

  if (t < 32) {
    float s = 0.f;
    #pragma unroll
    for (int p = 0; p < NSPLIT; ++p) s += cntpart[(size_t)p*8192 + rb + t];
    cntL[t] = (s == 0.f) ? 1.f : s;
  }
  __syncthreads();
  const float inv = 1.0f / cntL[r];
  float en = 0.f;
  #pragma unroll
  for (int jp = 0; jp < 4; ++jp) {    // 8 cols per iter
    float e8[8];
    #pragma unroll
    for (int q = 0; q < 2; ++q) {
      const float* p0 = part + (rb + r)*256 + c0 + jp*8 + q*4;
      float4 e4 = {0.f, 0.f, 0.f, 0.f};
      #pragma unroll
      for (int p = 0; p < NSPLIT; ++p) {
        float4 s0 = *(const float4*)(p0 + (size_t)p*2097152);
        e4.x += s0.x; e4.y += s0.y; e4.z += s0.z; e4.w += s0.w;
      }
      e4.x *= inv; e4.y *= inv; e4.z *= inv; e4.w *= inv;
      *(float4*)&eL[r][c0 + jp*8 + q*4] = e4;
      e8[q*4+0] = e4.x; e8[q*4+1] = e4.y; e8[q*4+2] = e4.z; e8[q*4+3] = e4.w;
    }
    u32 hw[4], lw[4];
    #pragma unroll
    for (int p = 0; p < 4; ++p) {
      float va = e8[2*p] - 0.5f, vb = e8[2*p+1] - 0.5f;
      split2(va, vb, hw[p], lw[p]);
      en += va*va + vb*vb;
    }
    const int slot = (t & 7)*4 + jp;                 // 0..31
    const int off  = r*512 + ((slot ^ (r & 7)) << 4);
    *(uint4*)(Eh + off) = make_uint4(hw[0],hw[1],hw[2],hw[3]);
    *(uint4*)(El + off) = make_uint4(lw[0],lw[1],lw[2],lw[3]);
  }
  enred[r][t & 7] = en;
  __syncthreads();
  if (t < 32) {
    float s = 0.f;
    #pragma unroll
    for (int j = 0; j < 8; ++j) s += enred[t][j];
    enL[t] = s;
  }
  // G = Ẽ · C̃^T via 3-pass split MFMA (16x16); wave w owns 128 centroids
  const int w = t >> 6, l = t & 63, lr = l & 15, lk = l >> 4;
  f32x4 acc[2][8];
  #pragma unroll
  for (int i = 0; i < 2; ++i)
    #pragma unroll
    for (int j = 0; j < 8; ++j) acc[i][j] = (f32x4){0.f,0.f,0.f,0.f};
  #pragma unroll
  for (int ksub = 0; ksub < 8; ++ksub) {
    bf16x8 ah[2], alo[2];
    #pragma unroll
    for (int mi = 0; mi < 2; ++mi) {
      const int row = mi*16 + lr;
      const int off = row*512 + (((ksub*4 + lk) ^ (row & 7)) << 4);
      ah[mi]  = *(const bf16x8*)(Eh + off);
      alo[mi] = *(const bf16x8*)(El + off);
    }
    bf16x8 bh[8], bl[8];
    #pragma unroll
    for (int ni = 0; ni < 8; ++ni) {
      const size_t fi = (((size_t)(w*8 + ni))*8 + ksub)*64 + l;
      bh[ni] = *(const bf16x8*)(CThi + fi*8);
      bl[ni] = *(const bf16x8*)(CTlo + fi*8);
    }
    #pragma unroll
    for (int mi = 0; mi < 2; ++mi)
      #pragma unroll
      for (int ni = 0; ni < 8; ++ni) {
        acc[mi][ni] = MFMA_B16(ah[mi],  bh[ni], acc[mi][ni]);
        acc[mi][ni] = MFMA_B16(alo[mi], bh[ni], acc[mi][ni]);
        acc[mi][ni] = MFMA_B16(ah[mi],  bl[ni], acc[mi][ni]);
      }
  }
  #pragma unroll
  for (int mi = 0; mi < 2; ++mi)
    #pragma unroll
    for (int ni = 0; ni < 8; ++ni)
      #pragma unroll
      for (int rr = 0; rr < 4; ++rr)
        GL[mi*16 + lk*4 + rr][w*128 + ni*16 + lr] = acc[mi][ni][rr];
  __syncthreads();
  // argmin (f64 combine; exact first-index tie-break) + blend + store; wave w rows w*8..w*8+7
  for (int i = 0; i < 8; ++i) {
    const int row = w*8 + i;
    const double en_ = (double)enL[row];
    double best = 1e300; int bk = 0;
    #pragma unroll
    for (int jj = 0; jj < 8; ++jj) {
      const int k = jj*64 + l;
      const double d2 = en_ + cnormd[k] - 2.0*(double)GL[row][k];
      if (d2 < best) { best = d2; bk = k; }
    }
    #pragma unroll
    for (int off = 32; off > 0; off >>= 1) {
      const double ov = __shfl_xor(best, off);
      const int   ok = __shfl_xor(bk, off);
      if (ov < best || (ov == best && ok < bk)) { best = ov; bk = ok; }
    }
    const float* crow = cent + (size_t)bk*256;
    float4 ef = *(const float4*)&eL[row][l*4];
    float4 cf = *(const float4*)(crow + l*4);
    float4 o;
    o.x = 0.1f*ef.x + 0.9f*cf.x;
    o.y = 0.1f*ef.y + 0.9f*cf.y;
    o.z = 0.1f*ef.z + 0.9f*cf.z;
    o.w = 0.1f*ef.w + 0.9f*cf.w;
    *(float4*)(out + (rb + row)*256 + l*4) = o;
  }
}

extern "C" void kernel_launch(void* const* d_in, const int* in_sizes, int n_in,
                              void* d_out, int out_size, void* d_ws, size_t ws_size,
                              hipStream_t stream) {
  const float* seq  = (const float*)d_in[0];
  const float* emb  = (const float*)d_in[1];
  const float* cent = (const float*)d_in[2];
  float* out = (float*)d_out;
  char* ws = (char*)d_ws;

  float*  part    = (float*) (ws);
  float*  cntpart = (float*) (ws + OFF_CNT);
  u16*    Bhi     = (u16*)   (ws + OFF_BHI);
  u16*    Blo     = (u16*)   (ws + OFF_BLO);
  u16*    CThi    = (u16*)   (ws + OFF_CTHI);
  u16*    CTlo    = (u16*)   (ws + OFF_CTLO);
  double* cnormd  = (double*)(ws + OFF_CNORM);

  hipLaunchKernelGGL(ce_prep, dim3(1152), dim3(256), 0, stream,
                     emb, cent, Bhi, Blo, CThi, CTlo, cnormd);
  hipLaunchKernelGGL(ce_gemm, dim3(512), dim3(512), 0, stream,
                     seq, Bhi, Blo, part, cntpart);
  hipLaunchKernelGGL(ce_cent, dim3(256), dim3(256), 0, stream,
                     part, cntpart, CThi, CTlo, cnormd, cent, out);
}

// Round 12
// 150.907 us; speedup vs baseline: 3.1474x; 3.1474x over previous
//
#include <hip/hip_runtime.h>

// ConceptEmbedding: out = 0.1*e_free + 0.9*centroid[argmin d2]
// e_free = (seq @ emb) / rowsum(seq);  seq [8192 x 8192] f32, emb [8192 x 256] f32
// Strategy: split-precision bf16 MFMA (hi/lo, 3 passes) ~= f32 accuracy.
//   K0: pack emb (32x32x16 frag order) and cent-0.5 (16x16 order); f64 cnorm.
//   K1: 8-phase-template port (T3+T4+T5). BM=128 x BN=256, split-K=4 (256 WGs =
//       1 block/CU), 8 waves = 2wm x 4wn, wave tile 64x64 (acc 64 AGPR) at
//       launch_bounds(512,2) -> 256-reg budget (R10/R11 spilled at the 128 cap).
//       K64 tiles double-buffered; 4 phases/tile:
//       {loadB(p+1) | stage-duty ; s_barrier ; setprio+12 MFMA ; ldsA(p+1) ; s_barrier}
//       Raw barriers (no vmcnt drain); lgkmcnt(0) once per tile before the
//       buffer-swap barrier. A staged in FRAGMENT ORDER -> all LDS ops linear,
//       conflict-free, no swizzle. T14 staging: issue@T-1.p3, convert+write@T.p1/p2.
//       Per phase/CU: MFMA 768 cyc vs LDS ~320 vs VALU ~100 -> MFMA-bound 2.4:1.
//   K2: reduce 4 partials -> e_free; mean-shifted MFMA vs centroids; f64 argmin; blend.

typedef unsigned short u16;
typedef unsigned int   u32;
using bf16x8 = __attribute__((ext_vector_type(8))) short;
using f32x4  = __attribute__((ext_vector_type(4))) float;
using f32x16 = __attribute__((ext_vector_type(16))) float;

#define MFMA_B16(A,B,C) __builtin_amdgcn_mfma_f32_16x16x32_bf16((A),(B),(C),0,0,0)
#define MFMA32(A,B,C)   __builtin_amdgcn_mfma_f32_32x32x16_bf16((A),(B),(C),0,0,0)

#define NSPLIT 4

static __device__ __forceinline__ u16 f2bf(float f){
  u32 u = __builtin_bit_cast(u32, f);
  u += 0x7FFFu + ((u >> 16) & 1u);   // RNE
  return (u16)(u >> 16);
}
static __device__ __forceinline__ u16 f2bf_fast(float f){
  u32 u = __builtin_bit_cast(u32, f);
  return (u16)((u + 0x8000u) >> 16); // round-nearest ties-away, branchless
}
static __device__ __forceinline__ float bf2f(u16 h){
  u32 u = ((u32)h) << 16;
  return __builtin_bit_cast(float, u);
}
static __device__ __forceinline__ void split2(float va, float vb, u32& hw, u32& lw){
  u16 ha = f2bf(va), hb = f2bf(vb);
  hw = (u32)ha | ((u32)hb << 16);
  lw = (u32)f2bf(va - bf2f(ha)) | ((u32)f2bf(vb - bf2f(hb)) << 16);
}
static __device__ __forceinline__ void split2f(float va, float vb, u32& hw, u32& lw){
  u16 ha = f2bf_fast(va), hb = f2bf_fast(vb);
  hw = (u32)ha | ((u32)hb << 16);
  lw = (u32)f2bf_fast(va - bf2f(ha)) | ((u32)f2bf_fast(vb - bf2f(hb)) << 16);
}

// ---------------- ws layout (bytes) ----------------
#define SZ_PART    ((size_t)NSPLIT*8192UL*256UL*4UL)   // 33,554,432  f32 partials [4][8192][256]
#define OFF_CNT    (SZ_PART)
#define SZ_CNT     ((size_t)NSPLIT*8192UL*4UL)
#define OFF_BHI    (OFF_CNT + SZ_CNT)
#define SZ_BHI     (8192UL*256UL*2UL)                  // 4 MB
#define OFF_BLO    (OFF_BHI + SZ_BHI)
#define OFF_CTHI   (OFF_BLO + SZ_BHI)
#define SZ_CT      (512UL*256UL*2UL)                   // 256 KB
#define OFF_CTLO   (OFF_CTHI + SZ_CT)
#define OFF_CNORM  (OFF_CTLO + SZ_CT)                  // 512 doubles

// ---------------- K0: pack B (32x32 order) / CT (16x16 order), cnorm ----------------
__global__ __launch_bounds__(256) void ce_prep(
    const float* __restrict__ emb, const float* __restrict__ cent,
    u16* __restrict__ Bhi, u16* __restrict__ Blo,
    u16* __restrict__ CThi, u16* __restrict__ CTlo,
    double* __restrict__ cnormd)
{
  const int b = blockIdx.x, t = threadIdx.x;
  const int l = t & 63;
  if (b < 1024) {
    // emb frag for 32x32x16: (nt 0..7, ksg 0..511): elem j = emb[ksg*16 + (l>>5)*8 + j][nt*32 + (l&31)]
    const int g  = b * 4 + (t >> 6);
    const int nt = g >> 9, ksg = g & 511;
    const int col = nt*32 + (l & 31);
    const int k0  = ksg*16 + (l >> 5)*8;
    u32 hw[4], lw[4];
    #pragma unroll
    for (int p = 0; p < 4; ++p) {
      float va = emb[(size_t)(k0 + 2*p    )*256 + col];
      float vb = emb[(size_t)(k0 + 2*p + 1)*256 + col];
      split2(va, vb, hw[p], lw[p]);
    }
    const size_t fi = ((size_t)nt*512 + ksg)*64 + l;
    *(uint4*)(Bhi + fi*8) = make_uint4(hw[0],hw[1],hw[2],hw[3]);
    *(uint4*)(Blo + fi*8) = make_uint4(lw[0],lw[1],lw[2],lw[3]);
  } else if (b < 1088) {               // cent^T frags (16x16 order; nt 0..31, ksg 0..7), shifted by -0.5
    const int lr = l & 15, lk = l >> 4;
    const int g  = (b - 1024) * 4 + (t >> 6);
    const int nt = g >> 3, ksg = g & 7;
    u32 hw[4], lw[4];
    #pragma unroll
    for (int p = 0; p < 4; ++p) {
      float va = cent[(size_t)(nt*16 + lr)*256 + ksg*32 + lk*8 + 2*p    ] - 0.5f;
      float vb = cent[(size_t)(nt*16 + lr)*256 + ksg*32 + lk*8 + 2*p + 1] - 0.5f;
      split2(va, vb, hw[p], lw[p]);
    }
    const size_t fi = ((size_t)nt*8 + ksg)*64 + l;
    *(uint4*)(CThi + fi*8) = make_uint4(hw[0],hw[1],hw[2],hw[3]);
    *(uint4*)(CTlo + fi*8) = make_uint4(lw[0],lw[1],lw[2],lw[3]);
  } else {                             // cnorm: |cent_k - 0.5|^2 in f64
    const int row = (b - 1088)*8 + (t >> 5);
    const int h = t & 31;
    double s = 0.0;
    #pragma unroll
    for (int j = 0; j < 8; ++j) {
      float x = cent[(size_t)row*256 + h*8 + j] - 0.5f;
      s += (double)x * (double)x;
    }
    #pragma unroll
    for (int off = 16; off > 0; off >>= 1) s += __shfl_xor(s, off);
    if (h == 0) cnormd[row] = s;
  }
}

// ---------------- K1: 8-phase split-bf16 GEMM (32x32x16), 256 WGs x 512 thr ----------------
// blk: mt = blk>>2 (row tile of 128), ks = blk&3 (K-quarter of 2048); K64 tiles, 32 tiles
__global__ __launch_bounds__(512, 2) void ce_gemm(
    const float* __restrict__ seq,
    const u16* __restrict__ Bhi, const u16* __restrict__ Blo,
    float* __restrict__ part, float* __restrict__ cntpart)
{
  __shared__ char Ah[2*16384];        // [buf][mi(4)][ksub(4)][fl(64)]x16B, fragment-order
  __shared__ char Al[2*16384];        // linear lane addressing -> conflict-free
  __shared__ float cntred[128][8];

  const int t   = threadIdx.x;
  const int blk = blockIdx.x;
  const int mt  = blk >> 2;
  const int ks  = blk & 3;
  const size_t rowBase = (size_t)mt * 128;

  // ---- staging ids (thread t stages fragment (mi=mh*2 / mh*2+1, ksub=sks, lane=fl)) ----
  const int fl  = t & 63;
  const int sks = (t >> 6) & 3;
  const int mh  = t >> 8;             // 0/1
  const int r0l = mh*64 + (fl & 31);
  const float* ap0 = seq + (rowBase + r0l     )*8192 + (size_t)ks*2048 + sks*16 + (fl>>5)*8;
  const float* ap1 = seq + (rowBase + r0l + 32)*8192 + (size_t)ks*2048 + sks*16 + (fl>>5)*8;
  const u32 w0off = (u32)(mh*2    )*4096 + (u32)sks*1024 + (u32)fl*16;
  const u32 w1off = (u32)(mh*2 + 1)*4096 + (u32)sks*1024 + (u32)fl*16;

  // ---- compute ids: 8 waves = 2 wm x 4 wn; wave tile 64 rows x 64 cols ----
  const int w = t >> 6, l = t & 63;
  const int wm = w & 1, wn = w >> 1;
  const int lrow = l & 31, lhi = l >> 5;
  const u32 rbase0 = (u32)(wm*2    )*4096 + (u32)l*16;
  const u32 rbase1 = (u32)(wm*2 + 1)*4096 + (u32)l*16;

  // ---- B byte offsets (advance 1024B per K16) ----
  const char* bhp = (const char*)Bhi;
  const char* blp = (const char*)Blo;
  u32 boff0 = (((u32)(wn*2    )*512 + (u32)ks*128)*64 + (u32)l)*16;
  u32 boff1 = (((u32)(wn*2 + 1)*512 + (u32)ks*128)*64 + (u32)l)*16;

  f32x16 a00, a01, a10, a11;
  #pragma unroll
  for (int i = 0; i < 16; ++i) { a00[i]=0.f; a01[i]=0.f; a10[i]=0.f; a11[i]=0.f; }

  float c0 = 0.f, c1 = 0.f;
  float4 g00, g01, g10, g11;          // staging f32 regs (one tile in flight)
  bf16x8 bA0h, bA0l, bA1h, bA1l;      // B set A
  bf16x8 bB0h, bB0l, bB1h, bB1l;      // B set B
  bf16x8 fA0h, fA0l, fA1h, fA1l;      // A-frag set A (mi local 0,1)
  bf16x8 fB0h, fB0l, fB1h, fB1l;      // A-frag set B

  auto issueA = [&](int tile) {
    const int o = tile*64;
    g00 = *(const float4*)(ap0 + o);  g01 = *(const float4*)(ap0 + o + 4);
    g10 = *(const float4*)(ap1 + o);  g11 = *(const float4*)(ap1 + o + 4);
  };
  auto writeHalf0 = [&](int buf) {
    float v[8] = {g00.x,g00.y,g00.z,g00.w,g01.x,g01.y,g01.z,g01.w};
    #pragma unroll
    for (int i = 0; i < 8; ++i) c0 += v[i];
    u32 hw[4], lw[4];
    #pragma unroll
    for (int p = 0; p < 4; ++p) split2f(v[2*p], v[2*p+1], hw[p], lw[p]);
    *(uint4*)(Ah + buf*16384 + w0off) = make_uint4(hw[0],hw[1],hw[2],hw[3]);
    *(uint4*)(Al + buf*16384 + w0off) = make_uint4(lw[0],lw[1],lw[2],lw[3]);
  };
  auto writeHalf1 = [&](int buf) {
    float v[8] = {g10.x,g10.y,g10.z,g10.w,g11.x,g11.y,g11.z,g11.w};
    #pragma unroll
    for (int i = 0; i < 8; ++i) c1 += v[i];
    u32 hw[4], lw[4];
    #pragma unroll
    for (int p = 0; p < 4; ++p) split2f(v[2*p], v[2*p+1], hw[p], lw[p]);
    *(uint4*)(Ah + buf*16384 + w1off) = make_uint4(hw[0],hw[1],hw[2],hw[3]);
    *(uint4*)(Al + buf*16384 + w1off) = make_uint4(lw[0],lw[1],lw[2],lw[3]);
  };
  auto loadB = [&](bf16x8& h0, bf16x8& l0, bf16x8& h1, bf16x8& l1) {
    h0 = *(const bf16x8*)(bhp + boff0);  l0 = *(const bf16x8*)(blp + boff0);
    h1 = *(const bf16x8*)(bhp + boff1);  l1 = *(const bf16x8*)(blp + boff1);
    boff0 += 1024; boff1 += 1024;
  };
  auto ldsA = [&](int buf, int ksub, bf16x8& h0, bf16x8& l0, bf16x8& h1, bf16x8& l1) {
    const u32 o0 = (u32)buf*16384 + rbase0 + (u32)ksub*1024;
    const u32 o1 = (u32)buf*16384 + rbase1 + (u32)ksub*1024;
    h0 = *(const bf16x8*)(Ah + o0);  l0 = *(const bf16x8*)(Al + o0);
    h1 = *(const bf16x8*)(Ah + o1);  l1 = *(const bf16x8*)(Al + o1);
  };
  auto mfma12 = [&](bf16x8 ah0, bf16x8 al0, bf16x8 ah1, bf16x8 al1,
                    bf16x8 b0h, bf16x8 b0l, bf16x8 b1h, bf16x8 b1l) {
    __builtin_amdgcn_s_setprio(1);
    a00 = MFMA32(ah0, b0h, a00);
    a01 = MFMA32(ah0, b1h, a01);
    a10 = MFMA32(ah1, b0h, a10);
    a11 = MFMA32(ah1, b1h, a11);
    a00 = MFMA32(al0, b0h, a00);
    a01 = MFMA32(al0, b1h, a01);
    a10 = MFMA32(al1, b0h, a10);
    a11 = MFMA32(al1, b1h, a11);
    a00 = MFMA32(ah0, b0l, a00);
    a01 = MFMA32(ah0, b1l, a01);
    a10 = MFMA32(ah1, b0l, a10);
    a11 = MFMA32(ah1, b1l, a11);
    __builtin_amdgcn_s_setprio(0);
  };
  #define SBAR() __builtin_amdgcn_s_barrier()
  #define TILE_FENCE() do { \
    asm volatile("s_waitcnt lgkmcnt(0)" ::: "memory"); \
    __builtin_amdgcn_sched_barrier(0); \
    __builtin_amdgcn_s_barrier(); \
    __builtin_amdgcn_sched_barrier(0); } while (0)

  // ---- prologue: stage tile 0 synchronously; issue tile-1 loads; first B ----
  issueA(0);
  writeHalf0(0);
  writeHalf1(0);
  issueA(1);
  loadB(bA0h, bA0l, bA1h, bA1l);      // ksg = ks*128 + 0
  TILE_FENCE();

  for (int tile = 0; tile < 32; ++tile) {
    const int cur = tile & 1;
    const int nxt = cur ^ 1;

    ldsA(cur, 0, fA0h, fA0l, fA1h, fA1l);
    // ---- phase 0 ----
    loadB(bB0h, bB0l, bB1h, bB1l);    // ksg +1
    SBAR();
    mfma12(fA0h, fA0l, fA1h, fA1l, bA0h, bA0l, bA1h, bA1l);
    ldsA(cur, 1, fB0h, fB0l, fB1h, fB1l);
    SBAR();
    // ---- phase 1 ----
    loadB(bA0h, bA0l, bA1h, bA1l);    // ksg +2
    if (tile < 31) writeHalf0(nxt);
    SBAR();
    mfma12(fB0h, fB0l, fB1h, fB1l, bB0h, bB0l, bB1h, bB1l);
    ldsA(cur, 2, fA0h, fA0l, fA1h, fA1l);
    SBAR();
    // ---- phase 2 ----
    loadB(bB0h, bB0l, bB1h, bB1l);    // ksg +3
    if (tile < 31) writeHalf1(nxt);
    SBAR();
    mfma12(fA0h, fA0l, fA1h, fA1l, bA0h, bA0l, bA1h, bA1l);
    ldsA(cur, 3, fB0h, fB0l, fB1h, fB1l);
    SBAR();
    // ---- phase 3 ----
    if (tile < 31) loadB(bA0h, bA0l, bA1h, bA1l);  // ksg +4 = next tile phase 0
    if (tile < 30) issueA(tile + 2);
    SBAR();
    mfma12(fB0h, fB0l, fB1h, fB1l, bB0h, bB0l, bB1h, bB1l);
    TILE_FENCE();                     // drain my ds_writes; swap buffers
  }

  // ---- row-count reduce: 8 stager threads per row ----
  __syncthreads();
  cntred[r0l     ][(t >> 5) & 7] = c0;
  cntred[r0l + 32][(t >> 5) & 7] = c1;
  __syncthreads();
  if (t < 128) {
    float c = 0.f;
    #pragma unroll
    for (int j = 0; j < 8; ++j) c += cntred[t][j];
    cntpart[(size_t)ks*8192 + rowBase + t] = c;
  }

  // ---- partial e_free store (32x32 C/D: col=l&31, row=(reg&3)+8*(reg>>2)+4*lhi) ----
  float* pbase = part + ((size_t)ks*8192 + rowBase)*256;
  #pragma unroll
  for (int reg = 0; reg < 16; ++reg) {
    const int rsub = (reg & 3) + 8*(reg >> 2) + 4*lhi;
    float* prow0 = pbase + (size_t)(wm*64 + rsub)*256 + wn*64 + lrow;
    float* prow1 = prow0 + 32*256;
    prow0[0]  = a00[reg];
    prow0[32] = a01[reg];
    prow1[0]  = a10[reg];
    prow1[32] = a11[reg];
  }
}

// ---------------- K2: reduce + centroid argmin + blend, 256 WGs x 256 thr ----------------
__global__ __launch_bounds__(256) void ce_cent(
    const float* __restrict__ part, const float* __restrict__ cntpart,
    const u16* __restrict__ CThi, const u16* __restrict__ CTlo,
    const double* __restrict__ cnormd, const float* __restrict__ cent,
    float* __restrict__ out)
{
  __shared__ float eL[32][256];       // e_free rows (f32)
  __shared__ char Eh[32*512];         // shifted e hi bf16, swizzled [row][256]
  __shared__ char El[32*512];
  __shared__ float GL[32][512];       // (e-.5)·(c-.5)^T
  __shared__ float cntL[32];
  __shared__ float enred[32][8];
  __shared__ float enL[32];

  const int t = threadIdx.x;
  const size_t rb = (size_t)blockIdx.x * 32;
  const int r  = t >> 3;
  const int c0 = (t & 7) * 32;

  if (t < 32) {
    float s = 0.f;
    #pragma unroll
    for (int p = 0; p < NSPLIT; ++p) s += cntpart[(size_t)p*8192 + rb + t];
    cntL[t] = (s == 0.f) ? 1.f : s;
  }
  __syncthreads();
  const float inv = 1.0f / cntL[r];
  float en = 0.f;
  #pragma unroll
  for (int jp = 0; jp < 4; ++jp) {    // 8 cols per iter
    float e8[8];
    #pragma unroll
    for (int q = 0; q < 2; ++q) {
      const float* p0 = part + (rb + r)*256 + c0 + jp*8 + q*4;
      float4 e4 = {0.f, 0.f, 0.f, 0.f};
      #pragma unroll
      for (int p = 0; p < NSPLIT; ++p) {
        float4 s0 = *(const float4*)(p0 + (size_t)p*2097152);
        e4.x += s0.x; e4.y += s0.y; e4.z += s0.z; e4.w += s0.w;
      }
      e4.x *= inv; e4.y *= inv; e4.z *= inv; e4.w *= inv;
      *(float4*)&eL[r][c0 + jp*8 + q*4] = e4;
      e8[q*4+0] = e4.x; e8[q*4+1] = e4.y; e8[q*4+2] = e4.z; e8[q*4+3] = e4.w;
    }
    u32 hw[4], lw[4];
    #pragma unroll
    for (int p = 0; p < 4; ++p) {
      float va = e8[2*p] - 0.5f, vb = e8[2*p+1] - 0.5f;
      split2(va, vb, hw[p], lw[p]);
      en += va*va + vb*vb;
    }
    const int slot = (t & 7)*4 + jp;                 // 0..31
    const int off  = r*512 + ((slot ^ (r & 7)) << 4);
    *(uint4*)(Eh + off) = make_uint4(hw[0],hw[1],hw[2],hw[3]);
    *(uint4*)(El + off) = make_uint4(lw[0],lw[1],lw[2],lw[3]);
  }
  enred[r][t & 7] = en;
  __syncthreads();
  if (t < 32) {
    float s = 0.f;
    #pragma unroll
    for (int j = 0; j < 8; ++j) s += enred[t][j];
    enL[t] = s;
  }
  // G = Ẽ · C̃^T via 3-pass split MFMA (16x16); wave w owns 128 centroids
  const int w = t >> 6, l = t & 63, lr = l & 15, lk = l >> 4;
  f32x4 acc[2][8];
  #pragma unroll
  for (int i = 0; i < 2; ++i)
    #pragma unroll
    for (int j = 0; j < 8; ++j) acc[i][j] = (f32x4){0.f,0.f,0.f,0.f};
  #pragma unroll
  for (int ksub = 0; ksub < 8; ++ksub) {
    bf16x8 ah[2], alo[2];
    #pragma unroll
    for (int mi = 0; mi < 2; ++mi) {
      const int row = mi*16 + lr;
      const int off = row*512 + (((ksub*4 + lk) ^ (row & 7)) << 4);
      ah[mi]  = *(const bf16x8*)(Eh + off);
      alo[mi] = *(const bf16x8*)(El + off);
    }
    bf16x8 bh[8], bl[8];
    #pragma unroll
    for (int ni = 0; ni < 8; ++ni) {
      const size_t fi = (((size_t)(w*8 + ni))*8 + ksub)*64 + l;
      bh[ni] = *(const bf16x8*)(CThi + fi*8);
      bl[ni] = *(const bf16x8*)(CTlo + fi*8);
    }
    #pragma unroll
    for (int mi = 0; mi < 2; ++mi)
      #pragma unroll
      for (int ni = 0; ni < 8; ++ni) {
        acc[mi][ni] = MFMA_B16(ah[mi],  bh[ni], acc[mi][ni]);
        acc[mi][ni] = MFMA_B16(alo[mi], bh[ni], acc[mi][ni]);
        acc[mi][ni] = MFMA_B16(ah[mi],  bl[ni], acc[mi][ni]);
      }
  }
  #pragma unroll
  for (int mi = 0; mi < 2; ++mi)
    #pragma unroll
    for (int ni = 0; ni < 8; ++ni)
      #pragma unroll
      for (int rr = 0; rr < 4; ++rr)
        GL[mi*16 + lk*4 + rr][w*128 + ni*16 + lr] = acc[mi][ni][rr];
  __syncthreads();
  // argmin (f64 combine; exact first-index tie-break) + blend + store; wave w rows w*8..w*8+7
  for (int i = 0; i < 8; ++i) {
    const int row = w*8 + i;
    const double en_ = (double)enL[row];
    double best = 1e300; int bk = 0;
    #pragma unroll
    for (int jj = 0; jj < 8; ++jj) {
      const int k = jj*64 + l;
      const double d2 = en_ + cnormd[k] - 2.0*(double)GL[row][k];
      if (d2 < best) { best = d2; bk = k; }
    }
    #pragma unroll
    for (int off = 32; off > 0; off >>= 1) {
      const double ov = __shfl_xor(best, off);
      const int   ok = __shfl_xor(bk, off);
      if (ov < best || (ov == best && ok < bk)) { best = ov; bk = ok; }
    }
    const float* crow = cent + (size_t)bk*256;
    float4 ef = *(const float4*)&eL[row][l*4];
    float4 cf = *(const float4*)(crow + l*4);
    float4 o;
    o.x = 0.1f*ef.x + 0.9f*cf.x;
    o.y = 0.1f*ef.y + 0.9f*cf.y;
    o.z = 0.1f*ef.z + 0.9f*cf.z;
    o.w = 0.1f*ef.w + 0.9f*cf.w;
    *(float4*)(out + (rb + row)*256 + l*4) = o;
  }
}

extern "C" void kernel_launch(void* const* d_in, const int* in_sizes, int n_in,
                              void* d_out, int out_size, void* d_ws, size_t ws_size,
                              hipStream_t stream) {
  const float* seq  = (const float*)d_in[0];
  const float* emb  = (const float*)d_in[1];
  const float* cent = (const float*)d_in[2];
  float* out = (float*)d_out;
  char* ws = (char*)d_ws;

  float*  part    = (float*) (ws);
  float*  cntpart = (float*) (ws + OFF_CNT);
  u16*    Bhi     = (u16*)   (ws + OFF_BHI);
  u16*    Blo     = (u16*)   (ws + OFF_BLO);
  u16*    CThi    = (u16*)   (ws + OFF_CTHI);
  u16*    CTlo    = (u16*)   (ws + OFF_CTLO);
  double* cnormd  = (double*)(ws + OFF_CNORM);

  hipLaunchKernelGGL(ce_prep, dim3(1152), dim3(256), 0, stream,
                     emb, cent, Bhi, Blo, CThi, CTlo, cnormd);
  hipLaunchKernelGGL(ce_gemm, dim3(256), dim3(512), 0, stream,
                     seq, Bhi, Blo, part, cntpart);
  hipLaunchKernelGGL(ce_cent, dim3(256), dim3(256), 0, stream,
                     part, cntpart, CThi, CTlo, cnormd, cent, out);
}